// Round 1
// baseline (3583.730 us; speedup 1.0000x reference)
//
#include <hip/hip_runtime.h>
#include <hip/hip_fp16.h>

#define BB 128
#define TT 2048
#define DD 64
#define HH 128
#define OO 32

// Stable fast tanh: tanh(u) = sign(u) * (1-e)/(1+e), e = exp(-2|u|).
__device__ __forceinline__ float fast_tanh(float u){
    float t = __expf(-2.f * fabsf(u));
    float r = (1.f - t) * __builtin_amdgcn_rcpf(1.f + t);
    return copysignf(r, u);
}

// Layer-0 scan. One block per batch row, 256 threads = 4 waves.
// wave w, lane l: output i = w*32 + (l&31); half = l>>5 splits the dot.
// W_hh0 half-row (64 f32) + W_ih0 half-row (32 f32) live in VGPRs.
// h in LDS; x[t] double-buffered in LDS (wave 0 prefetches t+1).
// For t >= len the hidden state is frozen and never observed -> stop at len.
extern "C" __global__ void __launch_bounds__(256)
scan0_kernel(const float* __restrict__ x, const int* __restrict__ lengths,
             const float* __restrict__ W_ih0, const float* __restrict__ W_hh0,
             const float* __restrict__ b_ih0, const float* __restrict__ b_hh0,
             __half* __restrict__ h1out)
{
    const int b    = blockIdx.x;
    const int tid  = threadIdx.x;
    const int w    = tid >> 6;
    const int l    = tid & 63;
    const int i    = (w << 5) | (l & 31);
    const int half = l >> 5;

    __shared__ float h_lds[HH];
    __shared__ float x_lds[2][DD];

    float whh[64];
    {
        const float4* wr = (const float4*)(W_hh0 + i*HH + half*64);
        #pragma unroll
        for (int j=0;j<16;++j){ float4 v = wr[j]; whh[4*j]=v.x; whh[4*j+1]=v.y; whh[4*j+2]=v.z; whh[4*j+3]=v.w; }
    }
    float wih[32];
    {
        const float4* wr = (const float4*)(W_ih0 + i*DD + half*32);
        #pragma unroll
        for (int j=0;j<8;++j){ float4 v = wr[j]; wih[4*j]=v.x; wih[4*j+1]=v.y; wih[4*j+2]=v.z; wih[4*j+3]=v.w; }
    }
    const float bsum = b_ih0[i] + b_hh0[i];
    const int len = lengths[b];
    const float* xrow = x + (size_t)b * (TT*DD);
    __half* h1row = h1out + (size_t)b * (TT*HH);

    if (tid < HH) h_lds[tid] = 0.f;
    if (tid < DD) x_lds[0][tid] = xrow[tid];
    __syncthreads();

    for (int t=0; t<len; ++t){
        const int cur = t & 1;
        float xpre = 0.f;
        const bool pf = (w==0) && (t+1 < len);
        if (pf) xpre = xrow[(t+1)*DD + l];   // l in [0,64) = D

        const float* hb = &h_lds[half*64];
        const float* xb = &x_lds[cur][half*32];
        float a0=0.f,a1=0.f,a2=0.f,a3=0.f;   // 4 chains to cover FMA latency
        #pragma unroll
        for (int j=0;j<64;j+=4){
            a0 += whh[j  ]*hb[j  ];
            a1 += whh[j+1]*hb[j+1];
            a2 += whh[j+2]*hb[j+2];
            a3 += whh[j+3]*hb[j+3];
        }
        #pragma unroll
        for (int j=0;j<32;j+=4){
            a0 += wih[j  ]*xb[j  ];
            a1 += wih[j+1]*xb[j+1];
            a2 += wih[j+2]*xb[j+2];
            a3 += wih[j+3]*xb[j+3];
        }
        float acc = (a0+a1)+(a2+a3);
        acc += __shfl_xor(acc, 32, 64);      // combine the two halves
        const float hn = fast_tanh(acc + bsum);
        __syncthreads();                     // everyone done reading h_lds/x_lds
        if (half==0){
            h_lds[i] = hn;
            h1row[(size_t)t*HH + i] = __float2half(hn);
        }
        if (pf) x_lds[cur^1][l] = xpre;
        __syncthreads();
    }
    // h1 rows for t >= len are never read by scan1 (it also stops at len).
}

// Layer-1 scan + fused fc. One block per row, 256 threads.
// W_hh1/W_ih1 half-rows in VGPRs (128 regs), W_fc 16-chunk in VGPRs.
// fc for step t-1 is computed at the start of step t (h_lds still = h2[t-1]),
// so it reuses the existing barrier. Tail t>=len: out = b_fc exactly.
extern "C" __global__ void __launch_bounds__(256)
scan1_kernel(const __half* __restrict__ h1, const int* __restrict__ lengths,
             const float* __restrict__ W_ih1, const float* __restrict__ W_hh1,
             const float* __restrict__ b_ih1, const float* __restrict__ b_hh1,
             const float* __restrict__ W_fc, const float* __restrict__ b_fc,
             float* __restrict__ out)
{
    const int b    = blockIdx.x;
    const int tid  = threadIdx.x;
    const int w    = tid >> 6;
    const int l    = tid & 63;
    const int i    = (w << 5) | (l & 31);
    const int half = l >> 5;
    const int o    = l & 31;

    __shared__ float h_lds[HH];
    __shared__ float h1_lds[2][HH];
    __shared__ float fcpart[4][OO];

    float whh[64], wih[64];
    {
        const float4* wr = (const float4*)(W_hh1 + i*HH + half*64);
        #pragma unroll
        for (int j=0;j<16;++j){ float4 v=wr[j]; whh[4*j]=v.x; whh[4*j+1]=v.y; whh[4*j+2]=v.z; whh[4*j+3]=v.w; }
        const float4* wr2 = (const float4*)(W_ih1 + i*HH + half*64);
        #pragma unroll
        for (int j=0;j<16;++j){ float4 v=wr2[j]; wih[4*j]=v.x; wih[4*j+1]=v.y; wih[4*j+2]=v.z; wih[4*j+3]=v.w; }
    }
    float wfc[16];  // wave w covers h-chunk [32w,32w+32), lane: o=l&31, sub=half
    {
        const float4* wr = (const float4*)(W_fc + o*HH + w*32 + half*16);
        #pragma unroll
        for (int j=0;j<4;++j){ float4 v=wr[j]; wfc[4*j]=v.x; wfc[4*j+1]=v.y; wfc[4*j+2]=v.z; wfc[4*j+3]=v.w; }
    }
    const float bsum = b_ih1[i] + b_hh1[i];
    const int len = lengths[b];
    const __half* h1row = h1 + (size_t)b*(TT*HH);
    float* orow = out + (size_t)b*(TT*OO);

    if (tid < HH){ h_lds[tid]=0.f; h1_lds[0][tid] = __half2float(h1row[tid]); }
    __syncthreads();

    for (int t=0; t<len; ++t){
        const int cur = t & 1;
        float h1pre = 0.f;
        const bool pf = (tid < HH) && (t+1 < len);
        if (pf) h1pre = __half2float(h1row[(size_t)(t+1)*HH + tid]);

        // fc for t-1 (h_lds holds h2[t-1])
        if (t > 0){
            float p = 0.f;
            const float* hfc = &h_lds[w*32 + half*16];
            #pragma unroll
            for (int k=0;k<16;++k) p += wfc[k]*hfc[k];
            p += __shfl_xor(p, 32, 64);
            if (half==0) fcpart[w][o] = p;
        }

        const float* hb  = &h_lds[half*64];
        const float* h1b = &h1_lds[cur][half*64];
        float a0=0.f,a1=0.f,a2=0.f,a3=0.f;
        #pragma unroll
        for (int j=0;j<64;j+=4){
            a0 += whh[j  ]*hb[j  ];
            a1 += whh[j+1]*hb[j+1];
            a2 += whh[j+2]*hb[j+2];
            a3 += whh[j+3]*hb[j+3];
        }
        #pragma unroll
        for (int j=0;j<64;j+=4){
            a0 += wih[j  ]*h1b[j  ];
            a1 += wih[j+1]*h1b[j+1];
            a2 += wih[j+2]*h1b[j+2];
            a3 += wih[j+3]*h1b[j+3];
        }
        float acc = (a0+a1)+(a2+a3);
        acc += __shfl_xor(acc, 32, 64);
        const float hn = fast_tanh(acc + bsum);
        __syncthreads();                         // barrier A
        if (t>0 && tid<OO)
            orow[(size_t)(t-1)*OO + tid] = fcpart[0][tid]+fcpart[1][tid]
                                         + fcpart[2][tid]+fcpart[3][tid] + b_fc[tid];
        if (half==0) h_lds[i] = hn;
        if (pf) h1_lds[cur^1][tid] = h1pre;
        __syncthreads();                         // barrier B
    }
    // epilogue fc for t = len-1
    {
        float p = 0.f;
        const float* hfc = &h_lds[w*32 + half*16];
        #pragma unroll
        for (int k=0;k<16;++k) p += wfc[k]*hfc[k];
        p += __shfl_xor(p, 32, 64);
        if (half==0) fcpart[w][o] = p;
        __syncthreads();
        if (tid<OO)
            orow[(size_t)(len-1)*OO + tid] = fcpart[0][tid]+fcpart[1][tid]
                                           + fcpart[2][tid]+fcpart[3][tid] + b_fc[tid];
    }
    // tail: padded steps are exactly b_fc
    for (int idx = len*OO + tid; idx < TT*OO; idx += 256)
        orow[idx] = b_fc[idx & (OO-1)];
}

extern "C" void kernel_launch(void* const* d_in, const int* in_sizes, int n_in,
                              void* d_out, int out_size, void* d_ws, size_t ws_size,
                              hipStream_t stream)
{
    const float* x       = (const float*)d_in[0];
    const int*   lengths = (const int*)  d_in[1];
    const float* W_ih0   = (const float*)d_in[2];
    const float* W_hh0   = (const float*)d_in[3];
    const float* b_ih0   = (const float*)d_in[4];
    const float* b_hh0   = (const float*)d_in[5];
    const float* W_ih1   = (const float*)d_in[6];
    const float* W_hh1   = (const float*)d_in[7];
    const float* b_ih1   = (const float*)d_in[8];
    const float* b_hh1   = (const float*)d_in[9];
    const float* W_fc    = (const float*)d_in[10];
    const float* b_fc    = (const float*)d_in[11];

    // h1 staged as fp16 in workspace: B*T*H*2 = 64 MiB.
    __half* h1ws = (__half*)d_ws;

    scan0_kernel<<<BB, 256, 0, stream>>>(x, lengths, W_ih0, W_hh0, b_ih0, b_hh0, h1ws);
    scan1_kernel<<<BB, 256, 0, stream>>>(h1ws, lengths, W_ih1, W_hh1, b_ih1, b_hh1,
                                         W_fc, b_fc, (float*)d_out);
}

// Round 2
// 1830.304 us; speedup vs baseline: 1.9580x; 1.9580x over previous
//
#include <hip/hip_runtime.h>
#include <hip/hip_fp16.h>

#define BB 128
#define TT 2048
#define DD 64
#define HH 128
#define OO 32

typedef _Float16 h2v __attribute__((ext_vector_type(2)));
union V16 { int4 v; h2v h[4]; };

__device__ __forceinline__ h2v pack2(float x, float y){
    h2v r; r[0] = (_Float16)x; r[1] = (_Float16)y; return r;
}

#if __has_builtin(__builtin_amdgcn_fdot2)
__device__ __forceinline__ float fdot2_(h2v a, h2v b, float c){
    return __builtin_amdgcn_fdot2(a, b, c, false);
}
#else
__device__ __forceinline__ float fdot2_(h2v a, h2v b, float c){
    return c + (float)a[0]*(float)b[0] + (float)a[1]*(float)b[1];
}
#endif

// Stable fast tanh: tanh(u) = sign(u) * (1-e)/(1+e), e = exp(-2|u|).
__device__ __forceinline__ float fast_tanh(float u){
    float t = __expf(-2.f * fabsf(u));
    float r = (1.f - t) * __builtin_amdgcn_rcpf(1.f + t);
    return copysignf(r, u);
}

// Fused 2-layer scan. One block per batch row, 512 threads = 8 waves.
// Waves 0-3 (grp=0): layer0 at step t.   Waves 4-7 (grp=1): layer1 at step t-1.
// All state double-buffered in LDS fp16; exactly ONE __syncthreads per iter.
// h1 never touches global. h2 streamed to global fp16 (lag 2) for the fc
// post-kernel. x prefetched 1 step ahead by grp0/wave0.
extern "C" __global__ void __launch_bounds__(512, 2)
fused_scan(const float* __restrict__ x, const int* __restrict__ lengths,
           const float* __restrict__ W_ih0, const float* __restrict__ W_hh0,
           const float* __restrict__ b_ih0, const float* __restrict__ b_hh0,
           const float* __restrict__ W_ih1, const float* __restrict__ W_hh1,
           const float* __restrict__ b_ih1, const float* __restrict__ b_hh1,
           __half* __restrict__ h2g)
{
    const int b    = blockIdx.x;
    const int tid  = threadIdx.x;
    const int grp  = tid >> 8;        // 0: layer0, 1: layer1
    const int wtid = tid & 255;
    const int w    = wtid >> 6;       // wave within group
    const int l    = wtid & 63;
    const int i    = (w << 5) | (l & 31);   // output index [0,128)
    const int half = l >> 5;                // k-split

    __shared__ __align__(16) __half h0buf[2][HH];
    __shared__ __align__(16) __half h1buf[2][HH];
    __shared__ __align__(16) __half h2buf[2][HH];
    __shared__ __align__(16) __half xbuf [2][DD];

    // ---- weight preload into registers (fp16 pairs) ----
    h2v whh[32];   // W_hh row i, k in [half*64, half*64+64)
    h2v wih[32];   // layer0: W_ih0 row i, k in [half*32,+32) (16 pairs); layer1: 32 pairs
    float bsum;
    if (grp == 0){
        const float* wr = W_hh0 + i*HH + half*64;
        #pragma unroll
        for (int j=0;j<16;++j){ float4 f = ((const float4*)wr)[j];
            whh[2*j] = pack2(f.x,f.y); whh[2*j+1] = pack2(f.z,f.w); }
        const float* wr2 = W_ih0 + i*DD + half*32;
        #pragma unroll
        for (int j=0;j<8;++j){ float4 f = ((const float4*)wr2)[j];
            wih[2*j] = pack2(f.x,f.y); wih[2*j+1] = pack2(f.z,f.w); }
        bsum = b_ih0[i] + b_hh0[i];
    } else {
        const float* wr = W_hh1 + i*HH + half*64;
        #pragma unroll
        for (int j=0;j<16;++j){ float4 f = ((const float4*)wr)[j];
            whh[2*j] = pack2(f.x,f.y); whh[2*j+1] = pack2(f.z,f.w); }
        const float* wr2 = W_ih1 + i*HH + half*64;
        #pragma unroll
        for (int j=0;j<16;++j){ float4 f = ((const float4*)wr2)[j];
            wih[2*j] = pack2(f.x,f.y); wih[2*j+1] = pack2(f.z,f.w); }
        bsum = b_ih1[i] + b_hh1[i];
    }

    const int len = lengths[b];
    const float* xrow = x + (size_t)b * (TT*DD);
    __half* h2row = h2g + (size_t)b * (TT*HH);

    // ---- init: zero states, stage x[0] ----
    if (tid < HH){ h0buf[0][tid] = __float2half(0.f); h2buf[0][tid] = __float2half(0.f); }
    if (tid < DD){ xbuf[0][tid] = __float2half(xrow[tid]); }
    __syncthreads();

    // ---- main loop: len+2 iterations, one barrier each ----
    for (int t = 0; t < len + 2; ++t){
        // x prefetch for t+1 (issue early)
        float xv = 0.f;
        const bool pfx = (grp==0) && (w==0) && (t+1 < len);
        if (pfx) xv = xrow[(t+1)*DD + l];

        // h2 streamer: store h2 after step (t-2), lag 2 (buffer written at t-1)
        if (grp==0 && w==1 && (unsigned)l < 32u && t >= 2){
            uint2 hv2 = *(const uint2*)&h2buf[(t-1)&1][l*4];
            *(uint2*)(h2row + (size_t)(t-2)*HH + l*4) = hv2;
        }

        const bool active = grp ? (t >= 1 && t <= len) : (t < len);
        float hn = 0.f;
        if (active){
            const int rp = (t - grp) & 1;   // read parity
            const __half* bufA = grp ? &h2buf[rp][0] : &h0buf[rp][0];
            const __half* bufB = grp ? &h1buf[rp][0] : &xbuf[rp][0];
            const int4* Ap = (const int4*)(bufA + half*64);
            float a0=0.f,a1=0.f,a2=0.f,a3=0.f;
            #pragma unroll
            for (int j=0;j<8;++j){
                V16 r; r.v = Ap[j];
                a0 = fdot2_(whh[4*j+0], r.h[0], a0);
                a1 = fdot2_(whh[4*j+1], r.h[1], a1);
                a2 = fdot2_(whh[4*j+2], r.h[2], a2);
                a3 = fdot2_(whh[4*j+3], r.h[3], a3);
            }
            if (grp){
                const int4* Bp = (const int4*)(bufB + half*64);
                #pragma unroll
                for (int j=0;j<8;++j){
                    V16 r; r.v = Bp[j];
                    a0 = fdot2_(wih[4*j+0], r.h[0], a0);
                    a1 = fdot2_(wih[4*j+1], r.h[1], a1);
                    a2 = fdot2_(wih[4*j+2], r.h[2], a2);
                    a3 = fdot2_(wih[4*j+3], r.h[3], a3);
                }
            } else {
                const int4* Bp = (const int4*)(bufB + half*32);
                #pragma unroll
                for (int j=0;j<4;++j){
                    V16 r; r.v = Bp[j];
                    a0 = fdot2_(wih[4*j+0], r.h[0], a0);
                    a1 = fdot2_(wih[4*j+1], r.h[1], a1);
                    a2 = fdot2_(wih[4*j+2], r.h[2], a2);
                    a3 = fdot2_(wih[4*j+3], r.h[3], a3);
                }
            }
            float acc = (a0+a1)+(a2+a3);
            acc += __shfl_xor(acc, 32, 64);
            hn = fast_tanh(acc + bsum);
        }

        // writes (double-buffered -> no read/write hazard before the barrier)
        if (active && half==0){
            __half hv = __float2half(hn);
            const int wp = (t + 1 - grp) & 1;
            if (grp) h2buf[wp][i] = hv;
            else    { h0buf[wp][i] = hv; h1buf[t&1][i] = hv; }
        }
        if (pfx) xbuf[(t+1)&1][l] = __float2half(xv);
        __syncthreads();
    }
}

// fc post-kernel: out[b,t,:] = W_fc . h2[b,t,:] + b_fc for t<len, else b_fc.
// Grid B*8 blocks x 256 threads; thread (r=tid>>5, o=tid&31); W_fc row o in
// registers (fp16 pairs); h2 rows staged in LDS (padded stride vs bank clash).
#define HP 136
extern "C" __global__ void __launch_bounds__(256)
fc_kernel(const __half* __restrict__ h2g, const int* __restrict__ lengths,
          const float* __restrict__ W_fc, const float* __restrict__ b_fc,
          float* __restrict__ out)
{
    const int b   = blockIdx.x >> 3;
    const int c   = blockIdx.x & 7;
    const int tid = threadIdx.x;
    const int r   = tid >> 5;
    const int o   = tid & 31;

    __shared__ __align__(16) __half hrow[8][HP];

    h2v wfc[64];
    {
        const float* wr = W_fc + o*HH;
        #pragma unroll
        for (int j=0;j<32;++j){ float4 f = ((const float4*)wr)[j];
            wfc[2*j] = pack2(f.x,f.y); wfc[2*j+1] = pack2(f.z,f.w); }
    }
    const float bo = b_fc[o];
    const int len = lengths[b];
    const int tbase = c * 256;

    for (int it = 0; it < 32; ++it){
        const int t0 = tbase + it*8;
        // stage 8 h2 rows (4 halves per thread)
        {
            const int idx = tid * 4;
            const int row = idx >> 7;
            const int k   = idx & 127;
            const int t   = t0 + row;
            if (t < len){
                const __half* src = h2g + ((size_t)b*TT + t)*HH + k;
                *(uint2*)&hrow[row][k] = *(const uint2*)src;
            }
        }
        __syncthreads();
        const int t = t0 + r;
        float* op = out + ((size_t)b*TT + t)*OO + o;
        if (t < len){
            const int4* hp = (const int4*)&hrow[r][0];
            float a0=bo, a1=0.f, a2=0.f, a3=0.f;
            #pragma unroll
            for (int j=0;j<16;++j){
                V16 rr; rr.v = hp[j];
                a0 = fdot2_(wfc[4*j+0], rr.h[0], a0);
                a1 = fdot2_(wfc[4*j+1], rr.h[1], a1);
                a2 = fdot2_(wfc[4*j+2], rr.h[2], a2);
                a3 = fdot2_(wfc[4*j+3], rr.h[3], a3);
            }
            *op = (a0+a1)+(a2+a3);
        } else {
            *op = bo;
        }
        __syncthreads();
    }
}

extern "C" void kernel_launch(void* const* d_in, const int* in_sizes, int n_in,
                              void* d_out, int out_size, void* d_ws, size_t ws_size,
                              hipStream_t stream)
{
    const float* x       = (const float*)d_in[0];
    const int*   lengths = (const int*)  d_in[1];
    const float* W_ih0   = (const float*)d_in[2];
    const float* W_hh0   = (const float*)d_in[3];
    const float* b_ih0   = (const float*)d_in[4];
    const float* b_hh0   = (const float*)d_in[5];
    const float* W_ih1   = (const float*)d_in[6];
    const float* W_hh1   = (const float*)d_in[7];
    const float* b_ih1   = (const float*)d_in[8];
    const float* b_hh1   = (const float*)d_in[9];
    const float* W_fc    = (const float*)d_in[10];
    const float* b_fc    = (const float*)d_in[11];

    // h2 staged as fp16 in workspace: B*T*H*2 = 64 MiB.
    __half* h2ws = (__half*)d_ws;

    fused_scan<<<BB, 512, 0, stream>>>(x, lengths, W_ih0, W_hh0, b_ih0, b_hh0,
                                       W_ih1, W_hh1, b_ih1, b_hh1, h2ws);
    fc_kernel<<<BB*8, 256, 0, stream>>>(h2ws, lengths, W_fc, b_fc, (float*)d_out);
}

// Round 3
// 1782.575 us; speedup vs baseline: 2.0104x; 1.0268x over previous
//
#include <hip/hip_runtime.h>

#define BB 128
#define TT 2048
#define DD 64
#define HH 128
#define OO 32

typedef _Float16 f16x8 __attribute__((ext_vector_type(8)));
typedef float    f32x4 __attribute__((ext_vector_type(4)));

#define MFMA16(a,b,c) __builtin_amdgcn_mfma_f32_16x16x32_f16((a),(b),(c),0,0,0)

__device__ __forceinline__ f32x4 load4(const float* p){ return *(const f32x4*)p; }

// A-fragment for 16x16x32: lane(n=lane&15,q=lane>>4) holds A[m=n][k=q*8+j].
// p points at W + row*ldk + kcol (8 consecutive fp32).
__device__ __forceinline__ f16x8 afrag(const float* p){
    float4 a = *(const float4*)p, b = *(const float4*)(p+4);
    f16x8 r;
    r[0]=(_Float16)a.x; r[1]=(_Float16)a.y; r[2]=(_Float16)a.z; r[3]=(_Float16)a.w;
    r[4]=(_Float16)b.x; r[5]=(_Float16)b.y; r[6]=(_Float16)b.z; r[7]=(_Float16)b.w;
    return r;
}

// tanh(u) = 1 - 2/(1 + e^{2u}) = 1 - 2*rcp(1 + exp2(u*2/ln2)); 5 VALU ops,
// saturates correctly at +/-1 for |u| large (inf -> rcp=0, 0 -> rcp(1)=1).
__device__ __forceinline__ float tanh5(float u){
#if __has_builtin(__builtin_amdgcn_exp2f)
    float e = __builtin_amdgcn_exp2f(u * 2.885390081777927f);
#else
    float e = exp2f(u * 2.885390081777927f);
#endif
    return __builtin_fmaf(-2.f, __builtin_amdgcn_rcpf(1.f + e), 1.f);
}

// ---------------------------------------------------------------------------
// proj: xp0[bt][i] = W_ih0[i,:].x[bt,:] + b_ih0[i] + b_hh0[i], fp16 out.
// 4096 blocks x 256 thr; each block: 64 (b,t) rows. Wave w: rows w*16..+16.
// ---------------------------------------------------------------------------
#define XSTR 72
extern "C" __global__ void __launch_bounds__(256)
proj_kernel(const float* __restrict__ x, const float* __restrict__ W_ih0,
            const float* __restrict__ b_ih0, const float* __restrict__ b_hh0,
            _Float16* __restrict__ xp0)
{
    const int tid = threadIdx.x;
    const int w = tid >> 6, lane = tid & 63;
    const int n = lane & 15, q = lane >> 4;
    const size_t row0 = (size_t)blockIdx.x * 64;

    __shared__ __align__(16) _Float16 XT[64][XSTR];

    #pragma unroll
    for (int it = 0; it < 4; ++it){
        float4 v = *(const float4*)(x + row0*DD + it*1024 + tid*4);
        int rr = it*16 + (tid >> 4), d0 = (tid & 15)*4;
        union { uint2 u; _Float16 h[4]; } c;
        c.h[0]=(_Float16)v.x; c.h[1]=(_Float16)v.y; c.h[2]=(_Float16)v.z; c.h[3]=(_Float16)v.w;
        *(uint2*)&XT[rr][d0] = c.u;
    }

    f16x8 A[8][2]; f32x4 bv[8];
    #pragma unroll
    for (int mt = 0; mt < 8; ++mt){
        #pragma unroll
        for (int kt = 0; kt < 2; ++kt)
            A[mt][kt] = afrag(W_ih0 + (mt*16 + n)*DD + kt*32 + q*8);
        bv[mt] = load4(b_ih0 + mt*16 + q*4) + load4(b_hh0 + mt*16 + q*4);
    }
    __syncthreads();

    const _Float16* xr = &XT[w*16 + n][0];
    f16x8 B0 = *(const f16x8*)(xr + q*8);
    f16x8 B1 = *(const f16x8*)(xr + 32 + q*8);

    _Float16* orow = xp0 + (row0 + w*16 + n)*HH + q*4;
    #pragma unroll
    for (int mt = 0; mt < 8; ++mt){
        f32x4 acc = bv[mt];
        acc = MFMA16(A[mt][0], B0, acc);
        acc = MFMA16(A[mt][1], B1, acc);
        union { uint2 u; _Float16 h[4]; } s;
        #pragma unroll
        for (int r = 0; r < 4; ++r) s.h[r] = (_Float16)acc[r];
        *(uint2*)(orow + mt*16) = s.u;
    }
}

// ---------------------------------------------------------------------------
// fill: out[b][t][:] = b_fc for t >= lengths[b]. Full-BW, disjoint from scan.
// ---------------------------------------------------------------------------
extern "C" __global__ void __launch_bounds__(256)
fill_kernel(const int* __restrict__ lengths, const float* __restrict__ b_fc,
            float* __restrict__ out)
{
    size_t idx = (size_t)blockIdx.x*256 + threadIdx.x;
    #pragma unroll
    for (int k = 0; k < 4; ++k, idx += (size_t)2048*256){
        int o4 = (int)(idx & 7);
        int t  = (int)((idx >> 3) & 2047);
        int b  = (int)(idx >> 14);
        if (t >= lengths[b])
            ((float4*)out)[idx] = *(const float4*)(b_fc + o4*4);
    }
}

// ---------------------------------------------------------------------------
// scan: 8 blocks x 256 thr (4 waves). Block = 16 batch rows (sorted lengths).
// Wave w owns m-tiles {2w, 2w+1} of the 128-dim h space.
// Iter t: Z0 -> H1[t] (= tanh(Whh0.H1[t-1] + xp0[t]));
//          Z1 -> H2[t-1] (= tanh(Wih1.H1[t-1] + Whh1.H2[t-2] + b1));
//          fc  -> out[t-2] (= Wfc.H2[t-2] + b_fc), waves 2-3 only.
// All three share the same 8 B-fragments (H1[t-1], H2[t-2]).
// One raw barrier per iter (lgkmcnt only; xp prefetch stays in flight).
// ---------------------------------------------------------------------------
#define NB   16
#define LSTR 136   // halves; 272B rows -> b128 frag reads tile all 32 banks

extern "C" __global__ void __launch_bounds__(256, 1)
scan_kernel(const _Float16* __restrict__ xp0, const int* __restrict__ lengths,
            const float* __restrict__ W_hh0,
            const float* __restrict__ W_ih1, const float* __restrict__ W_hh1,
            const float* __restrict__ b_ih1, const float* __restrict__ b_hh1,
            const float* __restrict__ W_fc,  const float* __restrict__ b_fc,
            float* __restrict__ out)
{
    const int tid  = threadIdx.x;
    const int w    = tid >> 6, lane = tid & 63;
    const int n    = lane & 15, q = lane >> 4;
    const int rbase= blockIdx.x * NB;

    __shared__ __align__(16) _Float16 H1T[2][NB][LSTR];
    __shared__ __align__(16) _Float16 H2T[2][NB][LSTR];

    // zero-init both parities of both state arrays
    for (int idx = tid; idx < 2*NB*LSTR/2; idx += 256){
        ((unsigned*)H1T)[idx] = 0u;
        ((unsigned*)H2T)[idx] = 0u;
    }

    // ---- stationary weights as A-fragments ----
    f16x8 A0[2][4], Ai[2][4], Ah[2][4];
    #pragma unroll
    for (int m = 0; m < 2; ++m){
        const int row = (2*w + m)*16 + n;
        #pragma unroll
        for (int kt = 0; kt < 4; ++kt){
            A0[m][kt] = afrag(W_hh0 + row*HH + kt*32 + q*8);
            Ai[m][kt] = afrag(W_ih1 + row*HH + kt*32 + q*8);
            Ah[m][kt] = afrag(W_hh1 + row*HH + kt*32 + q*8);
        }
    }
    const int f = w & 1;                 // fc m-tile for waves 2,3
    f16x8 Af[4];
    #pragma unroll
    for (int kt = 0; kt < 4; ++kt)
        Af[kt] = afrag(W_fc + (f*16 + n)*HH + kt*32 + q*8);

    f32x4 b1v[2];
    #pragma unroll
    for (int m = 0; m < 2; ++m)
        b1v[m] = load4(b_ih1 + (2*w+m)*16 + q*4) + load4(b_hh1 + (2*w+m)*16 + q*4);
    const f32x4 bfv = load4(b_fc + f*16 + q*4);

    // ---- lengths ----
    const int lenn = lengths[rbase + n];
    int mx = lenn;
    #pragma unroll
    for (int s = 1; s < 16; s <<= 1){ int o = __shfl_xor(mx, s, 64); mx = max(mx, o); }
    const int maxlen = __builtin_amdgcn_readfirstlane(mx);

    // ---- per-lane global pointers ----
    const _Float16* xpbase = xp0 + ((size_t)(rbase+n)*TT)*HH + (2*w)*16 + q*4;
    float* obase = out + ((size_t)(rbase+n)*TT)*OO + f*16 + q*4;

    // ---- xp0 prefetch (2 steps deep), mt0 at +0, mt1 at +16 halves ----
    uint2 xcA, xcB, xnA, xnB;
    xcA = *(const uint2*)(xpbase);            xcB = *(const uint2*)(xpbase + 16);
    if (1 < maxlen){ xnA = *(const uint2*)(xpbase + HH); xnB = *(const uint2*)(xpbase + HH + 16); }

    __syncthreads();   // init barrier (full)

    for (int t = 0; t <= maxlen + 1; ++t){
        const int p = t & 1, pn = p ^ 1;

        // B-fragments (shared by Z0, Z1, fc)
        f16x8 bh1[4], bh2[4];
        #pragma unroll
        for (int kt = 0; kt < 4; ++kt){
            bh1[kt] = *(const f16x8*)&H1T[p][n][kt*32 + q*8];
            bh2[kt] = *(const f16x8*)&H2T[p][n][kt*32 + q*8];
        }

        // ---- layer0: Z0 = Whh0 . H1[t-1] + xp0[t] ----
        f32x4 z0[2];
        const bool doZ0 = (t < maxlen);
        if (doZ0){
            {
                union { uint2 u; _Float16 h[4]; } cA, cB; cA.u = xcA; cB.u = xcB;
                #pragma unroll
                for (int r = 0; r < 4; ++r){ z0[0][r] = (float)cA.h[r]; z0[1][r] = (float)cB.h[r]; }
            }
            if (t + 2 < maxlen){
                xcA = *(const uint2*)(xpbase + (size_t)(t+2)*HH);
                xcB = *(const uint2*)(xpbase + (size_t)(t+2)*HH + 16);
            }
            #pragma unroll
            for (int kt = 0; kt < 4; ++kt){
                z0[0] = MFMA16(A0[0][kt], bh1[kt], z0[0]);
                z0[1] = MFMA16(A0[1][kt], bh1[kt], z0[1]);
            }
        }

        // ---- layer1: Z1 = Wih1 . H1[t-1] + Whh1 . H2[t-2] + b1 ----
        f32x4 z1[2];
        const bool doZ1 = (t >= 1) && (t <= maxlen);
        if (doZ1){
            z1[0] = b1v[0]; z1[1] = b1v[1];
            #pragma unroll
            for (int kt = 0; kt < 4; ++kt){
                z1[0] = MFMA16(Ai[0][kt], bh1[kt], z1[0]);
                z1[1] = MFMA16(Ai[1][kt], bh1[kt], z1[1]);
            }
            #pragma unroll
            for (int kt = 0; kt < 4; ++kt){
                z1[0] = MFMA16(Ah[0][kt], bh2[kt], z1[0]);
                z1[1] = MFMA16(Ah[1][kt], bh2[kt], z1[1]);
            }
        }

        // ---- fc: out[t-2] = Wfc . H2[t-2] + b_fc (waves 2,3) ----
        if (w >= 2 && t >= 2){
            f32x4 zf = bfv;
            #pragma unroll
            for (int kt = 0; kt < 4; ++kt) zf = MFMA16(Af[kt], bh2[kt], zf);
            if (t - 2 < lenn){
                float4 sv; sv.x = zf[0]; sv.y = zf[1]; sv.z = zf[2]; sv.w = zf[3];
                *(float4*)(obase + (size_t)(t-2)*OO) = sv;
            }
        }

        // ---- tanh + pack + state writes (into parity pn) ----
        if (doZ0){
            #pragma unroll
            for (int m = 0; m < 2; ++m){
                union { uint2 u; _Float16 h[4]; } s;
                #pragma unroll
                for (int r = 0; r < 4; ++r) s.h[r] = (_Float16)tanh5(z0[m][r]);
                *(uint2*)&H1T[pn][n][(2*w+m)*16 + q*4] = s.u;
            }
        }
        if (doZ1){
            #pragma unroll
            for (int m = 0; m < 2; ++m){
                union { uint2 u; _Float16 h[4]; } s;
                #pragma unroll
                for (int r = 0; r < 4; ++r) s.h[r] = (_Float16)tanh5(z1[m][r]);
                *(uint2*)&H2T[pn][n][(2*w+m)*16 + q*4] = s.u;
            }
        }

        // rotate xp prefetch buffers
        { uint2 tA = xcA; xcA = xnA; xnA = tA; uint2 tB = xcB; xcB = xnB; xnB = tB; }

        // barrier: drain LDS only; global prefetch/stores stay in flight
        asm volatile("s_waitcnt lgkmcnt(0)\n\ts_barrier" ::: "memory");
    }
}

// ---------------------------------------------------------------------------
extern "C" void kernel_launch(void* const* d_in, const int* in_sizes, int n_in,
                              void* d_out, int out_size, void* d_ws, size_t ws_size,
                              hipStream_t stream)
{
    const float* x       = (const float*)d_in[0];
    const int*   lengths = (const int*)  d_in[1];
    const float* W_ih0   = (const float*)d_in[2];
    const float* W_hh0   = (const float*)d_in[3];
    const float* b_ih0   = (const float*)d_in[4];
    const float* b_hh0   = (const float*)d_in[5];
    const float* W_ih1   = (const float*)d_in[6];
    const float* W_hh1   = (const float*)d_in[7];
    const float* b_ih1   = (const float*)d_in[8];
    const float* b_hh1   = (const float*)d_in[9];
    const float* W_fc    = (const float*)d_in[10];
    const float* b_fc    = (const float*)d_in[11];

    _Float16* xp = (_Float16*)d_ws;   // [B*T][128] fp16 = 64 MiB

    proj_kernel<<<BB*TT/64, 256, 0, stream>>>(x, W_ih0, b_ih0, b_hh0, xp);
    fill_kernel<<<2048, 256, 0, stream>>>(lengths, b_fc, (float*)d_out);
    scan_kernel<<<BB/NB, 256, 0, stream>>>(xp, lengths, W_hh0,
                                           W_ih1, W_hh1, b_ih1, b_hh1,
                                           W_fc, b_fc, (float*)d_out);
}